// Round 1
// baseline (274.472 us; speedup 1.0000x reference)
//
#include <hip/hip_runtime.h>

// Problem constants (fixed by setup_inputs)
#define B    8
#define L    4096
#define D    1024
#define NB   4
#define BS   (L / NB)        // 1024 rows per block
#define BN   (B * NB)        // 32 (b, nb) groups
#define RS   16              // row splits for pooling
#define ROWS_PER (BS / RS)   // 64 rows per partial block

// ---------------- Kernel 1: partial pooling sums ----------------
// grid: BN*RS blocks, 256 threads. Each block sums ROWS_PER rows x 1024 cols.
// Coalesced: thread t owns float4 column t (16B/lane).
__global__ void pool_partial(const float* __restrict__ x, float* __restrict__ partial) {
    int gid = blockIdx.x;
    int s   = gid & (RS - 1);     // row split
    int bn  = gid / RS;           // 0..31
    int t   = threadIdx.x;        // 0..255 -> float4 col

    const float4* xb = (const float4*)(x + (size_t)bn * BS * D + (size_t)s * ROWS_PER * D);
    float4 acc = make_float4(0.f, 0.f, 0.f, 0.f);
    #pragma unroll 4
    for (int r = 0; r < ROWS_PER; ++r) {
        float4 v = xb[(size_t)r * (D / 4) + t];
        acc.x += v.x; acc.y += v.y; acc.z += v.z; acc.w += v.w;
    }
    float4* p = (float4*)(partial + ((size_t)bn * RS + s) * D);
    p[t] = acc;
}

// ---------------- Kernel 2: fold partials -> pooled (mean) ----------------
// grid: BN blocks, 256 threads (float4 per thread)
__global__ void pool_reduce(const float* __restrict__ partial, float* __restrict__ pooled) {
    int bn = blockIdx.x;
    int t  = threadIdx.x;
    const float4* p = (const float4*)(partial + (size_t)bn * RS * D);
    float4 acc = make_float4(0.f, 0.f, 0.f, 0.f);
    #pragma unroll
    for (int s = 0; s < RS; ++s) {
        float4 v = p[(size_t)s * (D / 4) + t];
        acc.x += v.x; acc.y += v.y; acc.z += v.z; acc.w += v.w;
    }
    const float inv = 1.0f / (float)BS;
    float4* o = (float4*)(pooled + (size_t)bn * D);
    o[t] = make_float4(acc.x * inv, acc.y * inv, acc.z * inv, acc.w * inv);
}

// ---------------- Kernel 3: gate = sigmoid(pooled @ W^T + b) ----------------
// grid: BN*16 blocks (16 e-tiles of 64), 256 threads = 4 waves.
// Each wave computes 16 e values; per e: 64 lanes read W row coalesced
// (float4 each), dot with pooled, shfl-reduce.
__global__ void gate_kernel(const float* __restrict__ pooled, const float* __restrict__ W,
                            const float* __restrict__ bias, float* __restrict__ gate) {
    int blk   = blockIdx.x;
    int bn    = blk >> 4;
    int etile = blk & 15;            // 64 e's per block
    int t     = threadIdx.x;
    int wv    = t >> 6;              // wave id 0..3
    int lane  = t & 63;

    const float4* p4 = (const float4*)(pooled + (size_t)bn * D);

    for (int i = 0; i < 16; ++i) {
        int e = etile * 64 + wv * 16 + i;
        const float4* wr = (const float4*)(W + (size_t)e * D);
        float sum = 0.f;
        #pragma unroll
        for (int c = 0; c < 4; ++c) {
            float4 w = wr[c * 64 + lane];
            float4 p = p4[c * 64 + lane];
            sum += w.x * p.x + w.y * p.y + w.z * p.z + w.w * p.w;
        }
        #pragma unroll
        for (int off = 32; off; off >>= 1) sum += __shfl_down(sum, off);
        if (lane == 0) {
            sum += bias[e];
            gate[(size_t)bn * D + e] = 1.0f / (1.0f + __expf(-sum));
        }
    }
}

// ---------------- Kernel 4: out = x * gate (broadcast over block rows) ----
// grid-stride over float4 elements.
__global__ void apply_gate(const float* __restrict__ x, const float* __restrict__ gate,
                           float* __restrict__ out) {
    const size_t total4 = (size_t)B * L * D / 4;   // 8,388,608
    const float4* x4 = (const float4*)x;
    const float4* g4 = (const float4*)gate;
    float4* o4 = (float4*)out;

    for (size_t f = (size_t)blockIdx.x * blockDim.x + threadIdx.x; f < total4;
         f += (size_t)gridDim.x * blockDim.x) {
        size_t row = f >> 8;                         // global row 0..32767
        int bn = (int)((row >> 12) * NB + ((row >> 10) & (NB - 1)));
        float4 g = g4[(size_t)bn * (D / 4) + (f & 255)];
        float4 v = x4[f];
        o4[f] = make_float4(v.x * g.x, v.y * g.y, v.z * g.z, v.w * g.w);
    }
}

extern "C" void kernel_launch(void* const* d_in, const int* in_sizes, int n_in,
                              void* d_out, int out_size, void* d_ws, size_t ws_size,
                              hipStream_t stream) {
    const float* x    = (const float*)d_in[0];
    const float* W    = (const float*)d_in[1];
    const float* bias = (const float*)d_in[2];
    float* out        = (float*)d_out;

    // Workspace layout (floats):
    //   partial: BN*RS*D = 524288 floats (2 MB)
    //   pooled : BN*D    = 32768 floats (128 KB)
    //   gate   : BN*D    = 32768 floats (128 KB)
    float* partial = (float*)d_ws;
    float* pooled  = partial + (size_t)BN * RS * D;
    float* gate    = pooled + (size_t)BN * D;

    hipLaunchKernelGGL(pool_partial, dim3(BN * RS), dim3(256), 0, stream, x, partial);
    hipLaunchKernelGGL(pool_reduce,  dim3(BN),      dim3(256), 0, stream, partial, pooled);
    hipLaunchKernelGGL(gate_kernel,  dim3(BN * 16), dim3(256), 0, stream, pooled, W, bias, gate);
    hipLaunchKernelGGL(apply_gate,   dim3(4096),    dim3(256), 0, stream, x, gate, out);
}